// Round 3
// baseline (86.887 us; speedup 1.0000x reference)
//
#include <hip/hip_runtime.h>

#define N_ROWS 16384
#define L_DIM  4096
#define CG     16                 // W columns (locations) per bucket/block
#define JT     1024               // output-j columns per block
#define NBKT   (L_DIM / CG)       // 256 buckets
#define PITCH  (JT + 4)           // LDS row pitch (16B-aligned, conflict-free)

// ---------------- Kernel 0: zero the bucket counters ----------------
__global__ void zero_cnt(int* __restrict__ cnt) { cnt[threadIdx.x] = 0; }

// ---------------- Kernel 1: bucket rows by w[i]/CG, gather zw ----------------
// entry = { (c<<16)|i , bits(zw) }  where c = w[i] - bucket*CG
__global__ __launch_bounds__(256) void bucket_k(const int* __restrict__ w,
                                                const float* __restrict__ z,
                                                int* __restrict__ cnt,
                                                int2* __restrict__ entries,
                                                int cap) {
    const int i   = blockIdx.x * 256 + threadIdx.x;
    const int wi  = w[i];
    const float zw = z[(size_t)i * L_DIM + wi];
    const int bkt = wi >> 4;                     // / CG
    const int c   = wi & (CG - 1);
    const int pos = atomicAdd(&cnt[bkt], 1);
    if (pos < cap)
        entries[(size_t)bkt * cap + pos] = make_int2(i | (c << 16), __float_as_int(zw));
}

// ---------------- Kernel 2: out[i, j0:j0+JT] = zw * Wt_tile[c,:] + b ----------------
__global__ __launch_bounds__(256, 2) void pnet_main(const float* __restrict__ W,
                                                    const float* __restrict__ b,
                                                    const int* __restrict__ cnt,
                                                    const int2* __restrict__ entries,
                                                    float* __restrict__ out,
                                                    int cap) {
    __shared__ float tile[CG * PITCH];   // tile[c*PITCH + r] = W[j0+r][l0+c]
    const int bkt = blockIdx.x;
    const int l0  = bkt * CG;
    const int j0  = blockIdx.y * JT;
    const int tid = threadIdx.x;

    // ---- stage W tile: coalesced float4 reads (full 64B lines), transposed
    //      scalar LDS writes (measured-free 2-way banking) ----
    {
        const int q     = tid & 3;
        const int rbase = tid >> 2;
        #pragma unroll
        for (int it = 0; it < JT / 64; ++it) {
            const int r = rbase + it * 64;
            const float4 v = *(const float4*)&W[(size_t)(j0 + r) * L_DIM + l0 + 4 * q];
            tile[(4 * q + 0) * PITCH + r] = v.x;
            tile[(4 * q + 1) * PITCH + r] = v.y;
            tile[(4 * q + 2) * PITCH + r] = v.z;
            tile[(4 * q + 3) * PITCH + r] = v.w;
        }
    }

    const int wid  = tid >> 6;
    const int lane = tid & 63;
    float4 bb[4];
    #pragma unroll
    for (int k = 0; k < 4; ++k)
        bb[k] = *(const float4*)&b[j0 + (k * 64 + lane) * 4];

    int n = cnt[bkt];
    if (n > cap) n = cap;

    __syncthreads();

    // ---- stream matched rows; no barriers, no atomics ----
    const int2* __restrict__ bl = &entries[(size_t)bkt * cap];
    for (int e = wid; e < n; e += 4) {
        const int2  ent = bl[e];
        const int   i   = ent.x & 0xFFFF;
        const int   c   = ent.x >> 16;
        const float zw  = __int_as_float(ent.y);
        const float* __restrict__ trow = &tile[c * PITCH];
        float*       __restrict__ orow = &out[(size_t)i * L_DIM + j0];
        #pragma unroll
        for (int k = 0; k < 4; ++k) {
            const int jj = (k * 64 + lane) * 4;
            const float4 wv4 = *(const float4*)&trow[jj];   // ds_read_b128, conflict-free
            float4 o;
            o.x = fmaf(zw, wv4.x, bb[k].x);
            o.y = fmaf(zw, wv4.y, bb[k].y);
            o.z = fmaf(zw, wv4.z, bb[k].z);
            o.w = fmaf(zw, wv4.w, bb[k].w);
            *(float4*)&orow[jj] = o;                        // coalesced 1KB/wave stores
        }
    }
}

extern "C" void kernel_launch(void* const* d_in, const int* in_sizes, int n_in,
                              void* d_out, int out_size, void* d_ws, size_t ws_size,
                              hipStream_t stream) {
    const int*   w = (const int*)d_in[0];
    const float* z = (const float*)d_in[1];
    const float* W = (const float*)d_in[2];
    const float* b = (const float*)d_in[3];
    float* out = (float*)d_out;

    int*  cnt     = (int*)d_ws;
    int2* entries = (int2*)((char*)d_ws + 1024);

    // per-bucket capacity; N_ROWS is the absolute worst case (all rows one bucket).
    size_t cap_sz = (ws_size - 1024) / ((size_t)NBKT * sizeof(int2));
    int cap = (cap_sz > N_ROWS) ? N_ROWS : (int)cap_sz;

    zero_cnt<<<1, NBKT, 0, stream>>>(cnt);
    bucket_k<<<N_ROWS / 256, 256, 0, stream>>>(w, z, cnt, entries, cap);
    dim3 grid(NBKT, L_DIM / JT);   // (256, 4)
    pnet_main<<<grid, 256, 0, stream>>>(W, b, cnt, entries, out, cap);
}

// Round 4
// 79.222 us; speedup vs baseline: 1.0968x; 1.0968x over previous
//
#include <hip/hip_runtime.h>

#define N_ROWS 16384
#define L_DIM  4096
#define CG     16                 // locations per block
#define JT     1024               // output-j columns per block
#define NBKT   (L_DIM / CG)       // 256
#define PITCH  (JT + 4)           // 16B-aligned rows; stage writes 2-way banked (free)
#define CAP    1792               // LDS list capacity (bucket ~Poisson(64); max ~110)

// out[i, j] = z[i, w[i]] * W[j, w[i]] + b[j]
// One kernel. Block (g, t): locations l0=g*CG.., j-range j0=t*JT..
// 1) scan all of w[] once into an LDS match-list (overlaps with W-tile staging)
// 2) one barrier
// 3) stream matched rows: ds_read_b128 + fma + coalesced float4 stores, no syncs.
__global__ __launch_bounds__(256, 2) void pnet_fused(
    const int* __restrict__ w,
    const float* __restrict__ z,
    const float* __restrict__ W,
    const float* __restrict__ b,
    float* __restrict__ out)
{
    __shared__ float tile[CG * PITCH];   // tile[c*PITCH + r] = W[j0+r][l0+c]
    __shared__ int2  list[CAP];          // { i | (c<<16), bits(zw) }
    __shared__ int   cnt;

    const int tid  = threadIdx.x;
    const int l0   = blockIdx.x * CG;
    const int j0   = blockIdx.y * JT;
    const int wid  = tid >> 6;
    const int lane = tid & 63;

    if (tid == 0) cnt = 0;

    float4 bb[4];
    #pragma unroll
    for (int k = 0; k < 4; ++k)
        bb[k] = *(const float4*)&b[j0 + (k * 64 + lane) * 4];

    __syncthreads();  // cnt initialized

    // ---- scan w[] (once), append matches + gather zw; long-latency z loads
    //      issue before staging so they overlap it ----
    #pragma unroll
    for (int s = 0; s < N_ROWS / 1024; ++s) {
        const int i0  = s * 1024 + tid * 4;
        const int4 wv = *(const int4*)&w[i0];
        const int vals[4] = {wv.x, wv.y, wv.z, wv.w};
        #pragma unroll
        for (int e = 0; e < 4; ++e) {
            const unsigned c = (unsigned)(vals[e] - l0);
            if (c < CG) {
                const int pos = atomicAdd(&cnt, 1);
                if (pos < CAP)
                    list[pos] = make_int2((i0 + e) | ((int)c << 16),
                                          __float_as_int(z[(size_t)(i0 + e) * L_DIM + vals[e]]));
            }
        }
    }

    // ---- stage W tile: coalesced float4 reads, transposed scalar LDS writes ----
    {
        const int q     = tid & 3;
        const int rbase = tid >> 2;
        #pragma unroll
        for (int it = 0; it < JT / 64; ++it) {
            const int r = rbase + it * 64;
            const float4 v = *(const float4*)&W[(size_t)(j0 + r) * L_DIM + l0 + 4 * q];
            tile[(4 * q + 0) * PITCH + r] = v.x;
            tile[(4 * q + 1) * PITCH + r] = v.y;
            tile[(4 * q + 2) * PITCH + r] = v.z;
            tile[(4 * q + 3) * PITCH + r] = v.w;
        }
    }

    __syncthreads();  // tile + list ready
    const int n     = cnt;
    const int nmain = n < CAP ? n : CAP;

    // ---- stream matched rows; no barriers, no atomics ----
    for (int e = wid; e < nmain; e += 4) {
        const int2  ent = list[e];
        const int   i   = ent.x & 0xFFFF;
        const int   c   = ent.x >> 16;
        const float zw  = __int_as_float(ent.y);
        const float* __restrict__ trow = &tile[c * PITCH];
        float*       __restrict__ orow = &out[(size_t)i * L_DIM + j0];
        #pragma unroll
        for (int k = 0; k < 4; ++k) {
            const int jj = (k * 64 + lane) * 4;
            const float4 wv4 = *(const float4*)&trow[jj];   // ds_read_b128, conflict-free
            float4 o;
            o.x = fmaf(zw, wv4.x, bb[k].x);
            o.y = fmaf(zw, wv4.y, bb[k].y);
            o.z = fmaf(zw, wv4.z, bb[k].z);
            o.w = fmaf(zw, wv4.w, bb[k].w);
            *(float4*)&orow[jj] = o;                        // coalesced 1KB/wave stores
        }
    }

    // ---- overflow fallback (never fires for this input; idempotent rewrite) ----
    if (n > CAP) {
        for (int p = 0; p < N_ROWS / 1024; ++p) {
            __syncthreads();
            if (tid == 0) cnt = 0;
            __syncthreads();
            const int i0  = p * 1024 + tid * 4;
            const int4 wv = *(const int4*)&w[i0];
            const int vals[4] = {wv.x, wv.y, wv.z, wv.w};
            #pragma unroll
            for (int e = 0; e < 4; ++e) {
                const unsigned c = (unsigned)(vals[e] - l0);
                if (c < CG) {
                    const int pos = atomicAdd(&cnt, 1);   // ≤1024 per pass, fits CAP
                    list[pos] = make_int2((i0 + e) | ((int)c << 16),
                                          __float_as_int(z[(size_t)(i0 + e) * L_DIM + vals[e]]));
                }
            }
            __syncthreads();
            const int np = cnt;
            for (int e = wid; e < np; e += 4) {
                const int2  ent = list[e];
                const int   i   = ent.x & 0xFFFF;
                const int   c   = ent.x >> 16;
                const float zw  = __int_as_float(ent.y);
                const float* __restrict__ trow = &tile[c * PITCH];
                float*       __restrict__ orow = &out[(size_t)i * L_DIM + j0];
                #pragma unroll
                for (int k = 0; k < 4; ++k) {
                    const int jj = (k * 64 + lane) * 4;
                    const float4 wv4 = *(const float4*)&trow[jj];
                    float4 o;
                    o.x = fmaf(zw, wv4.x, bb[k].x);
                    o.y = fmaf(zw, wv4.y, bb[k].y);
                    o.z = fmaf(zw, wv4.z, bb[k].z);
                    o.w = fmaf(zw, wv4.w, bb[k].w);
                    *(float4*)&orow[jj] = o;
                }
            }
        }
    }
}

extern "C" void kernel_launch(void* const* d_in, const int* in_sizes, int n_in,
                              void* d_out, int out_size, void* d_ws, size_t ws_size,
                              hipStream_t stream) {
    const int*   w = (const int*)d_in[0];
    const float* z = (const float*)d_in[1];
    const float* W = (const float*)d_in[2];
    const float* b = (const float*)d_in[3];
    float* out = (float*)d_out;

    dim3 grid(NBKT, L_DIM / JT);   // (256, 4)
    pnet_fused<<<grid, 256, 0, stream>>>(w, z, W, b, out);
}

// Round 5
// 78.980 us; speedup vs baseline: 1.1001x; 1.0031x over previous
//
#include <hip/hip_runtime.h>

#define N_ROWS 16384
#define L_DIM  4096
#define CG     16                 // locations per block
#define JT     1024               // output-j columns per block
#define NBKT   (L_DIM / CG)       // 256
#define PITCH  (JT + 4)           // 16B-aligned rows; stage writes 2-way banked (free)
#define CAP    1792               // list capacity (bucket ~Poisson(64), max ~110)

// out[i, j] = z[i, w[i]] * W[j, w[i]] + b[j]
// Block (g, t): locations l0=g*CG.., j-range j0=t*JT..
// Phase 1: stage W tile (HBM loads issued first) + scan w[] into LDS list
//          (scan is pure L2 + LDS append — NO long-latency gathers).
// Phase 2: cooperative zw gather — one lane per entry, all loads in flight at once.
// Phase 3: stream matched rows — ds_read_b128 + fma + coalesced float4 stores.
__global__ __launch_bounds__(256, 2) void pnet_fused(
    const int* __restrict__ w,
    const float* __restrict__ z,
    const float* __restrict__ W,
    const float* __restrict__ b,
    float* __restrict__ out)
{
    __shared__ float tile[CG * PITCH];   // tile[c*PITCH + r] = W[j0+r][l0+c]
    __shared__ int   list[CAP];          // i | (c<<16)
    __shared__ float zlist[CAP];
    __shared__ int   cnt;

    const int tid  = threadIdx.x;
    const int l0   = blockIdx.x * CG;
    const int j0   = blockIdx.y * JT;
    const int wid  = tid >> 6;
    const int lane = tid & 63;

    if (tid == 0) cnt = 0;

    float4 bb[4];
    #pragma unroll
    for (int k = 0; k < 4; ++k)
        bb[k] = *(const float4*)&b[j0 + (k * 64 + lane) * 4];

    __syncthreads();  // cnt ready

    // ---- stage W tile: coalesced float4 HBM reads, transposed LDS writes ----
    {
        const int q     = tid & 3;
        const int rbase = tid >> 2;
        #pragma unroll
        for (int it = 0; it < JT / 64; ++it) {
            const int r = rbase + it * 64;
            const float4 v = *(const float4*)&W[(size_t)(j0 + r) * L_DIM + l0 + 4 * q];
            tile[(4 * q + 0) * PITCH + r] = v.x;
            tile[(4 * q + 1) * PITCH + r] = v.y;
            tile[(4 * q + 2) * PITCH + r] = v.z;
            tile[(4 * q + 3) * PITCH + r] = v.w;
        }
    }

    // ---- scan w[] once: append packed entries only (L2-fast, no gathers) ----
    #pragma unroll
    for (int s = 0; s < N_ROWS / 1024; ++s) {
        const int i0  = s * 1024 + tid * 4;
        const int4 wv = *(const int4*)&w[i0];
        const int vals[4] = {wv.x, wv.y, wv.z, wv.w};
        #pragma unroll
        for (int e = 0; e < 4; ++e) {
            const unsigned c = (unsigned)(vals[e] - l0);
            if (c < CG) {
                const int pos = atomicAdd(&cnt, 1);
                if (pos < CAP) list[pos] = (i0 + e) | ((int)c << 16);
            }
        }
    }

    __syncthreads();  // tile + list ready
    const int n     = cnt;
    const int nmain = n < CAP ? n : CAP;

    // ---- cooperative zw gather: every entry's load in flight simultaneously ----
    for (int e = tid; e < nmain; e += 256) {
        const int ent = list[e];
        const int i   = ent & 0xFFFF;
        const int c   = ent >> 16;
        zlist[e] = z[(size_t)i * L_DIM + l0 + c];
    }
    __syncthreads();  // zlist ready

    // ---- stream matched rows; no barriers, no atomics ----
    for (int e = wid; e < nmain; e += 4) {
        const int   ent = list[e];
        const int   i   = ent & 0xFFFF;
        const int   c   = ent >> 16;
        const float zw  = zlist[e];
        const float* __restrict__ trow = &tile[c * PITCH];
        float*       __restrict__ orow = &out[(size_t)i * L_DIM + j0];
        #pragma unroll
        for (int k = 0; k < 4; ++k) {
            const int jj = (k * 64 + lane) * 4;
            const float4 wv4 = *(const float4*)&trow[jj];   // ds_read_b128, conflict-free
            float4 o;
            o.x = fmaf(zw, wv4.x, bb[k].x);
            o.y = fmaf(zw, wv4.y, bb[k].y);
            o.z = fmaf(zw, wv4.z, bb[k].z);
            o.w = fmaf(zw, wv4.w, bb[k].w);
            *(float4*)&orow[jj] = o;                        // coalesced 1KB/wave stores
        }
    }

    // ---- overflow fallback (unreachable for this input; kept for correctness) ----
    if (n > CAP) {
        for (int p = 0; p < N_ROWS / 1024; ++p) {
            __syncthreads();
            if (tid == 0) cnt = 0;
            __syncthreads();
            const int i0  = p * 1024 + tid * 4;
            const int4 wv = *(const int4*)&w[i0];
            const int vals[4] = {wv.x, wv.y, wv.z, wv.w};
            #pragma unroll
            for (int e = 0; e < 4; ++e) {
                const unsigned c = (unsigned)(vals[e] - l0);
                if (c < CG) {
                    const int pos = atomicAdd(&cnt, 1);   // ≤1024 per pass ≤ CAP
                    list[pos]  = (i0 + e) | ((int)c << 16);
                    zlist[pos] = z[(size_t)(i0 + e) * L_DIM + vals[e]];
                }
            }
            __syncthreads();
            const int np = cnt;
            for (int e = wid; e < np; e += 4) {
                const int   ent = list[e];
                const int   i   = ent & 0xFFFF;
                const int   c   = ent >> 16;
                const float zw  = zlist[e];
                const float* __restrict__ trow = &tile[c * PITCH];
                float*       __restrict__ orow = &out[(size_t)i * L_DIM + j0];
                #pragma unroll
                for (int k = 0; k < 4; ++k) {
                    const int jj = (k * 64 + lane) * 4;
                    const float4 wv4 = *(const float4*)&trow[jj];
                    float4 o;
                    o.x = fmaf(zw, wv4.x, bb[k].x);
                    o.y = fmaf(zw, wv4.y, bb[k].y);
                    o.z = fmaf(zw, wv4.z, bb[k].z);
                    o.w = fmaf(zw, wv4.w, bb[k].w);
                    *(float4*)&orow[jj] = o;
                }
            }
        }
    }
}

extern "C" void kernel_launch(void* const* d_in, const int* in_sizes, int n_in,
                              void* d_out, int out_size, void* d_ws, size_t ws_size,
                              hipStream_t stream) {
    const int*   w = (const int*)d_in[0];
    const float* z = (const float*)d_in[1];
    const float* W = (const float*)d_in[2];
    const float* b = (const float*)d_in[3];
    float* out = (float*)d_out;

    dim3 grid(NBKT, L_DIM / JT);   // (256, 4)
    pnet_fused<<<grid, 256, 0, stream>>>(w, z, W, b, out);
}